// Round 1
// baseline (173.674 us; speedup 1.0000x reference)
//
#include <hip/hip_runtime.h>
#include <hip/hip_bf16.h>
#include <math.h>

// N=768, H=4, D=3, HDIM=64, HID=64. e_in[i,j] = [sqn(4) | hc[j](80) | hc[i](80)]
// z0 = sqn@W0a + Bj[j] + Bi[i]  (Bi includes b0 and the hc[i] half).
// Round 16: occupancy-tail fix. r14 geometry had 2304 blocks over 1024 resident
// slots (4 blk/CU LDS cap) = 2.25 rounds -> ~1/3 of runtime in a 1-blk/CU drain
// (Occupancy 36% avg vs 50% cap). Now: 3-wave blocks (192 thr, 192 pairs),
// grid (4,768)=3072 blocks; ybuf stride 72->64 with XOR slot-swizzle
// (slot ^= row&7 at 16B grain) -> 26.3 KB/block -> 6 blk/CU = 18 waves/CU,
// 3072/1536 resident = exactly 2 rounds, no tail. Per-wave work unchanged
// (64 pairs/wave). Biases folded into MFMA C-init (~200 VALU/lane saved).
//
// ws layout (float offsets):
#define WS_BJ    0         // Bj [768][64] f32
#define WS_BI    49152     // Bi [768][64] f32
#define WS_W0AT  98304     // W0a^T [64][4] f32
#define WS_BIAS  98560     // [224] f32: eb1@0, xb0@64, infb@128, 0, xb1@144, xb2@208, 0
#define WS_INFW  98784     // infw [64] f32
#define WS_WG    98848     // bf16 [224 rows][64]: W1^T@0, X0^T@64, infw@128, 0, X1^T@144, X2^T@208, 0
#define WS_PM    106016    // m_i partials [768][4][64] f32
#define WS_PS    302624    // shift partials [768][4][12] f32  (ends 339488)

typedef unsigned short ushort_t;
typedef __attribute__((ext_vector_type(8))) __bf16 bf16x8;
typedef __attribute__((ext_vector_type(4))) float f32x4;

__device__ __forceinline__ float silu_f(float v) {
    return v * __builtin_amdgcn_rcpf(1.0f + __expf(-v));
}
__device__ __forceinline__ float sigm_f(float v) {
    return __builtin_amdgcn_rcpf(1.0f + __expf(-v));
}

__device__ __forceinline__ ushort_t bf16r(float f) {
    unsigned u = __float_as_uint(f);
    u += 0x7FFFu + ((u >> 16) & 1u);
    return (ushort_t)(u >> 16);
}
__device__ __forceinline__ float bf2f(ushort_t s) { return __uint_as_float(((unsigned)s) << 16); }

__device__ __forceinline__ unsigned pk2(float a, float b) {
    __hip_bfloat162 t = __float22bfloat162_rn(make_float2(a, b));
    return *reinterpret_cast<unsigned*>(&t);
}

// swizzled element offset of the 8-ushort (16B) slot `slot` in row `row`
// of a [64][64] ushort tile. XOR by row&7 spreads the 8 slot-columns across
// banks for the strided (row-varying) access patterns.
__device__ __forceinline__ int ybo(int row, int slot) {
    return row * 64 + (((slot) ^ (row & 7)) << 3);
}
// f32 view of slot 0 of a row (16B = float4), same swizzle
__device__ __forceinline__ int yfo(int row) {
    return row * 32 + ((row & 7) << 2);
}

// ---------------- prep (256-thread blocks) ----------------
__global__ __launch_bounds__(256) void prep_kernel(
    const float* __restrict__ x, const float* __restrict__ h,
    const float* __restrict__ ew0, const float* __restrict__ eb0,
    const float* __restrict__ ew1, const float* __restrict__ eb1,
    const float* __restrict__ infw, const float* __restrict__ infb,
    const float* __restrict__ xw0, const float* __restrict__ xb0,
    const float* __restrict__ xw1, const float* __restrict__ xb1,
    const float* __restrict__ xw2, const float* __restrict__ xb2,
    float* __restrict__ ws)
{
    const int blk = blockIdx.x, tid = threadIdx.x;
    const int wv = tid >> 6, t = tid & 63;
    if (blk < 192) {
        __shared__ float hcs[4][80];
        const int m = blk * 4 + wv;
        hcs[wv][t] = h[m * 64 + t];
        if (t < 16) {
            int i2 = t >> 2, j2 = t & 3;
            float d0 = x[m*12 + j2*3 + 0] - x[m*12 + i2*3 + 0];
            float d1 = x[m*12 + j2*3 + 1] - x[m*12 + i2*3 + 1];
            float d2 = x[m*12 + j2*3 + 2] - x[m*12 + i2*3 + 2];
            hcs[wv][64 + t] = d0*d0 + d1*d1 + d2*d2;
        }
        float bj = 0.0f, bi = eb0[t];
        #pragma unroll 4
        for (int k = 0; k < 80; ++k) {
            float hv = hcs[wv][k];
            bj += hv * ew0[(4 + k) * 64 + t];
            bi += hv * ew0[(84 + k) * 64 + t];
        }
        ws[WS_BJ + m * 64 + t] = bj;
        ws[WS_BI + m * 64 + t] = bi;
    } else if (blk == 192) {
        if (wv == 0) {
            #pragma unroll
            for (int hh = 0; hh < 4; ++hh) ws[WS_W0AT + t * 4 + hh] = ew0[hh * 64 + t];
            ws[WS_INFW + t] = infw[t];
            #pragma unroll
            for (int u = 0; u < 4; ++u) {
                int idx = u * 64 + t;
                if (idx < 224) {
                    float v;
                    if (idx < 64)        v = eb1[idx];
                    else if (idx < 128)  v = xb0[idx - 64];
                    else if (idx == 128) v = infb[0];
                    else if (idx < 144)  v = 0.0f;
                    else if (idx < 208)  v = xb1[idx - 144];
                    else if (idx < 212)  v = xb2[idx - 208];
                    else                 v = 0.0f;
                    ws[WS_BIAS + idx] = v;
                }
            }
        }
    } else {
        ushort_t* wg = (ushort_t*)(ws + WS_WG);
        #pragma unroll 1
        for (int u = 0; u < 8; ++u) {
            int e = (blk - 193) * 2048 + tid * 8 + u;   // < 14336
            int r = e >> 6, k = e & 63;
            float v;
            if (r < 64)        v = ew1[k * 64 + r];
            else if (r < 128)  v = xw0[k * 64 + (r - 64)];
            else if (r == 128) v = infw[k];
            else if (r < 144)  v = 0.0f;
            else if (r < 208)  v = xw1[k * 64 + (r - 144)];
            else if (r < 212)  v = xw2[k * 4 + (r - 208)];
            else               v = 0.0f;
            wg[e] = bf16r(v);
        }
    }
}

// B-frags from per-wave swizzled LDS activations [p][k] (stride 64, xor slots)
__device__ __forceinline__ void load_bfrags(const ushort_t* yb, int ml, int q, bf16x8 B[4][2]) {
    #pragma unroll
    for (int pt = 0; pt < 4; ++pt)
        #pragma unroll
        for (int kt = 0; kt < 2; ++kt)
            B[pt][kt] = *(const bf16x8*)(yb + ybo(pt*16 + ml, kt*4 + q));
}

template<int NMT>
__device__ __forceinline__ void gemmG(const ushort_t* __restrict__ wg, int ml, int q,
                                      const bf16x8 B[4][2], f32x4* acc) {
    #pragma unroll
    for (int mt = 0; mt < NMT; ++mt) {
        #pragma unroll
        for (int kt = 0; kt < 2; ++kt) {
            bf16x8 af = *(const bf16x8*)(wg + (mt*16 + ml) * 64 + kt*32 + q*8);
            #pragma unroll
            for (int pt = 0; pt < 4; ++pt)
                acc[mt*4 + pt] = __builtin_amdgcn_mfma_f32_16x16x32_bf16(af, B[pt][kt], acc[mt*4 + pt], 0, 0, 0);
        }
    }
}

// bias already folded into acc init; just silu+pack+store (swizzled)
__device__ __forceinline__ void ep_silu2(ushort_t* yb, int ml, int q,
                                         const f32x4* acc, int coff) {
    #pragma unroll
    for (int mt = 0; mt < 2; ++mt) {
        #pragma unroll
        for (int pt = 0; pt < 4; ++pt) {
            f32x4 a = acc[mt*4 + pt];
            uint2 w = make_uint2(pk2(silu_f(a[0]), silu_f(a[1])),
                                 pk2(silu_f(a[2]), silu_f(a[3])));
            int row  = pt*16 + ml;
            int slot = (coff >> 3) + mt*2 + (q >> 1);
            *(uint2*)(yb + ybo(row, slot) + (q & 1) * 4) = w;
        }
    }
}

__device__ __forceinline__ void layer64(ushort_t* yb, const ushort_t* __restrict__ wg,
                                        const float* __restrict__ bias, int ml, int q) {
    bf16x8 B[4][2];
    load_bfrags(yb, ml, q, B);
    f32x4 acc[8];
    #pragma unroll
    for (int mt = 0; mt < 2; ++mt) {
        float4 bv = *(const float4*)(bias + mt*16 + q*4);
        #pragma unroll
        for (int pt = 0; pt < 4; ++pt) acc[mt*4 + pt] = f32x4{bv.x, bv.y, bv.z, bv.w};
    }
    gemmG<2>(wg, ml, q, B, acc);
    ep_silu2(yb, ml, q, acc, 0);
    #pragma unroll
    for (int mt = 0; mt < 2; ++mt) {
        float4 bv = *(const float4*)(bias + 32 + mt*16 + q*4);
        #pragma unroll
        for (int pt = 0; pt < 4; ++pt) acc[mt*4 + pt] = f32x4{bv.x, bv.y, bv.z, bv.w};
    }
    gemmG<2>(wg + 32*64, ml, q, B, acc);
    ep_silu2(yb, ml, q, acc, 32);
}

// ---------------- chunk kernel: block = (chunk it, row i), 192 pairs, 3 waves ----------------
__global__ __launch_bounds__(192, 4) void egcl_chunk(
    const float* __restrict__ x, float* __restrict__ ws)
{
    __shared__ __align__(16) ushort_t ybuf[3][4096];   // per-wave acts [64 p][64], 8 KB each
    __shared__ float sbuf[3][64];
    __shared__ float redm[3][64];
    __shared__ float reds[3][12];

    const int it = blockIdx.x, i = blockIdx.y, tid = threadIdx.x;
    const int wv = tid >> 6, lane = tid & 63;
    const int ml = lane & 15, q = lane >> 4;
    const int jg = it * 192 + wv * 64 + lane;

    const ushort_t* wg = (const ushort_t*)(ws + WS_WG);
    const float* bias  = ws + WS_BIAS;
    const float* infwf = ws + WS_INFW;
    ushort_t* yb = ybuf[wv];

    float xi[12];
    #pragma unroll
    for (int t = 0; t < 12; ++t) xi[t] = x[i * 12 + t];

    float sqn[4];
    {
        const float4* xp = (const float4*)(x + jg * 12);
        float4 a = xp[0], b = xp[1], c = xp[2];
        float d0, d1, d2;
        d0=a.x-xi[0]; d1=a.y-xi[1]; d2=a.z-xi[2];   sqn[0]=d0*d0+d1*d1+d2*d2;
        d0=a.w-xi[3]; d1=b.x-xi[4]; d2=b.y-xi[5];   sqn[1]=d0*d0+d1*d1+d2*d2;
        d0=b.z-xi[6]; d1=b.w-xi[7]; d2=c.x-xi[8];   sqn[2]=d0*d0+d1*d1+d2*d2;
        d0=c.y-xi[9]; d1=c.z-xi[10];d2=c.w-xi[11];  sqn[3]=d0*d0+d1*d1+d2*d2;
    }

    // ---- phi_e L0 (VALU, K=4 + Bi + Bj); write y0[p=lane][k] b128-packed ----
    {
        const float* Bi   = ws + WS_BI + i * 64;   // uniform -> s_load
        const float* w0at = ws + WS_W0AT;          // uniform -> s_load
        const float* Bj   = ws + WS_BJ + jg * 64;
        #pragma unroll
        for (int b = 0; b < 8; ++b) {
            float4 A = *(const float4*)(Bj + b*8);
            float4 Bv = *(const float4*)(Bj + b*8 + 4);
            float z[8] = {A.x, A.y, A.z, A.w, Bv.x, Bv.y, Bv.z, Bv.w};
            #pragma unroll
            for (int u = 0; u < 8; ++u) {
                int l = b*8 + u;
                float v = Bi[l] + z[u]
                        + sqn[0]*w0at[l*4+0] + sqn[1]*w0at[l*4+1]
                        + sqn[2]*w0at[l*4+2] + sqn[3]*w0at[l*4+3];
                z[u] = silu_f(v);
            }
            uint4 pkv = make_uint4(pk2(z[0],z[1]), pk2(z[2],z[3]),
                                   pk2(z[4],z[5]), pk2(z[6],z[7]));
            *(uint4*)(yb + ybo(lane, b)) = pkv;
        }
    }

    // ---- phi_e L1: m = silu(y0 @ W1 + b1) ----
    layer64(yb, wg + 0, bias + 0, ml, q);        // m -> yb

    // ---- phi_inf VALU row-dot: s_inf[p=lane] = infb + infw . m[lane][:] ----
    {
        float sv = bias[128];
        #pragma unroll
        for (int c = 0; c < 8; ++c) {
            int base = ybo(lane, c);
            uint2 w0 = *(const uint2*)(yb + base);
            uint2 w1 = *(const uint2*)(yb + base + 4);
            sv += __uint_as_float(w0.x << 16)          * infwf[c*8 + 0];
            sv += __uint_as_float(w0.x & 0xFFFF0000u)  * infwf[c*8 + 1];
            sv += __uint_as_float(w0.y << 16)          * infwf[c*8 + 2];
            sv += __uint_as_float(w0.y & 0xFFFF0000u)  * infwf[c*8 + 3];
            sv += __uint_as_float(w1.x << 16)          * infwf[c*8 + 4];
            sv += __uint_as_float(w1.x & 0xFFFF0000u)  * infwf[c*8 + 5];
            sv += __uint_as_float(w1.y << 16)          * infwf[c*8 + 6];
            sv += __uint_as_float(w1.y & 0xFFFF0000u)  * infwf[c*8 + 7];
        }
        sbuf[wv][lane] = (jg == i) ? 0.0f : sigm_f(sv);
    }

    // ---- m_i partial: lane=l sums e_p * m[p][l] (m still in yb) ----
    float macc = 0.0f;
    {
        const int g = lane >> 3, l7 = lane & 7;
        #pragma unroll 8
        for (int j2 = 0; j2 < 64; ++j2) {
            float ev = sbuf[wv][j2];
            macc += ev * bf2f(yb[j2*64 + (((g ^ (j2 & 7)) << 3) + l7)]);
        }
    }

    // ---- phi_x L0, L1 ----
    layer64(yb, wg + 64*64, bias + 64, ml, q);   // y1 -> yb
    layer64(yb, wg + 144*64, bias + 144, ml, q); // y2 -> yb

    // ---- phi_x L2 (64 -> 4); p overlaid into dead yb as f32 ----
    float* yf = (float*)yb;
    {
        bf16x8 B[4][2];
        load_bfrags(yb, ml, q, B);
        f32x4 acc2[4];
        float4 bx2 = *(const float4*)(bias + 208);
        #pragma unroll
        for (int t = 0; t < 4; ++t) acc2[t] = f32x4{bx2.x, bx2.y, bx2.z, bx2.w};
        gemmG<1>(wg + 208*64, ml, q, B, acc2);
        if (q == 0) {
            #pragma unroll
            for (int pt = 0; pt < 4; ++pt) {
                int row = pt*16 + ml;
                *(float4*)(yf + yfo(row)) =
                    make_float4(acc2[pt][0], acc2[pt][1], acc2[pt][2], acc2[pt][3]);
            }
        }
    }

    // ---- shift contributions (lane = p); butterfly -> reds ----
    {
        float4 pv = *(const float4*)(yf + yfo(lane));
        float pvh[4] = {pv.x, pv.y, pv.z, pv.w};
        float mask = (jg == i) ? 0.0f : 1.0f;
        const float4* xp = (const float4*)(x + jg * 12);
        float4 a = xp[0], b = xp[1], c = xp[2];
        float dxs[12];
        dxs[0]=a.x-xi[0]; dxs[1]=a.y-xi[1]; dxs[2]=a.z-xi[2];  dxs[3]=a.w-xi[3];
        dxs[4]=b.x-xi[4]; dxs[5]=b.y-xi[5]; dxs[6]=b.z-xi[6];  dxs[7]=b.w-xi[7];
        dxs[8]=c.x-xi[8]; dxs[9]=c.y-xi[9]; dxs[10]=c.z-xi[10];dxs[11]=c.w-xi[11];
        float s12[12];
        #pragma unroll
        for (int hh = 0; hh < 4; ++hh) {
            float nsq = (sqn[hh] == 0.0f) ? 1.0f : sqn[hh];
            float inv = mask * pvh[hh] * __builtin_amdgcn_rcpf(sqrtf(nsq) + 1.0f);
            #pragma unroll
            for (int d = 0; d < 3; ++d)
                s12[hh*3 + d] = dxs[hh*3 + d] * inv;
        }
        #pragma unroll
        for (int t = 0; t < 12; ++t) {
            float v = s12[t];
            v += __shfl_xor(v, 1, 64);
            v += __shfl_xor(v, 2, 64);
            v += __shfl_xor(v, 4, 64);
            v += __shfl_xor(v, 8, 64);
            v += __shfl_xor(v, 16, 64);
            v += __shfl_xor(v, 32, 64);
            if (lane == 0) reds[wv][t] = v;
        }
    }

    redm[wv][lane] = macc;
    __syncthreads();

    if (wv == 0) {
        ws[WS_PM + (i*4 + it)*64 + lane] =
            redm[0][lane] + redm[1][lane] + redm[2][lane];
        if (lane < 12)
            ws[WS_PS + (i*4 + it)*12 + lane] =
                reds[0][lane] + reds[1][lane] + reds[2][lane];
    }
}

// ---------------- finish: sum partials + phi_h + x_new (4 nodes/block) ----------------
__global__ __launch_bounds__(256) void finish_kernel(
    const float* __restrict__ x, const float* __restrict__ h,
    const float* __restrict__ hw0, const float* __restrict__ hb0,
    const float* __restrict__ hw1, const float* __restrict__ hb1,
    const float* __restrict__ hw2, const float* __restrict__ hb2,
    const float* __restrict__ ws, float* __restrict__ out)
{
    __shared__ float inbuf[4][128];
    __shared__ float zbuf[4][64];
    const int tid = threadIdx.x;
    const int wv = tid >> 6, lane = tid & 63;
    const int i = blockIdx.x * 4 + wv;

    const float* pm = ws + WS_PM + i*4*64;
    float mi = (pm[lane] + pm[64 + lane] + pm[128 + lane] + pm[192 + lane])
               * (1.0f / sqrtf(767.0f));
    inbuf[wv][lane] = mi;
    inbuf[wv][64 + lane] = h[i*64 + lane];

    if (lane < 12) {
        const float* ps = ws + WS_PS + i*4*12;
        float sh = ps[lane] + ps[12 + lane] + ps[24 + lane] + ps[36 + lane];
        out[i*12 + lane] = x[i*12 + lane] + sh * (1.0f / 767.0f);
    }

    // single wave per node: LDS ops in-order, no barrier needed
    float a = hb0[lane];
    #pragma unroll 8
    for (int k = 0; k < 128; ++k) a += inbuf[wv][k] * hw0[k*64 + lane];
    zbuf[wv][lane] = silu_f(a);

    a = hb1[lane];
    #pragma unroll 8
    for (int k = 0; k < 64; ++k) a += zbuf[wv][k] * hw1[k*64 + lane];
    zbuf[wv][lane] = silu_f(a);

    a = hb2[lane];
    #pragma unroll 8
    for (int k = 0; k < 64; ++k) a += zbuf[wv][k] * hw2[k*64 + lane];
    out[9216 + i*64 + lane] = h[i*64 + lane] + a;
}

extern "C" void kernel_launch(void* const* d_in, const int* in_sizes, int n_in,
                              void* d_out, int out_size, void* d_ws, size_t ws_size,
                              hipStream_t stream) {
    const float* x    = (const float*)d_in[0];
    const float* h    = (const float*)d_in[1];
    const float* ew0  = (const float*)d_in[2];
    const float* eb0  = (const float*)d_in[3];
    const float* ew1  = (const float*)d_in[4];
    const float* eb1  = (const float*)d_in[5];
    const float* infw = (const float*)d_in[6];
    const float* infb = (const float*)d_in[7];
    const float* xw0  = (const float*)d_in[8];
    const float* xb0  = (const float*)d_in[9];
    const float* xw1  = (const float*)d_in[10];
    const float* xb1  = (const float*)d_in[11];
    const float* xw2  = (const float*)d_in[12];
    const float* xb2  = (const float*)d_in[13];
    const float* hw0  = (const float*)d_in[14];
    const float* hb0  = (const float*)d_in[15];
    const float* hw1  = (const float*)d_in[16];
    const float* hb1  = (const float*)d_in[17];
    const float* hw2  = (const float*)d_in[18];
    const float* hb2  = (const float*)d_in[19];

    float* ws  = (float*)d_ws;
    float* out = (float*)d_out;

    prep_kernel<<<200, 256, 0, stream>>>(x, h, ew0, eb0, ew1, eb1, infw, infb,
                                         xw0, xb0, xw1, xb1, xw2, xb2, ws);
    egcl_chunk<<<dim3(4, 768), 192, 0, stream>>>(x, ws);
    finish_kernel<<<192, 256, 0, stream>>>(x, h, hw0, hb0, hw1, hb1, hw2, hb2, ws, out);
}

// Round 2
// 172.062 us; speedup vs baseline: 1.0094x; 1.0094x over previous
//
#include <hip/hip_runtime.h>
#include <hip/hip_bf16.h>
#include <math.h>

// N=768, H=4, D=3, HDIM=64, HID=64. e_in[i,j] = [sqn(4) | hc[j](80) | hc[i](80)]
// z0 = sqn@W0a + Bj[j] + Bi[i]  (Bi includes b0 and the hc[i] half).
// Round 17: consolidation. r16's geometry change (3-wave/grid(4,768)) regressed
// (78.9 vs 74.8; resident waves DROPPED 11.5->10.3 despite 26.6KB LDS -> the
// ~12-wave/CU cap is geometry-insensitive; pool is effectively ~128KB or
// WG-sched-limited). Revert to proven r14 geometry (4-wave, 256 pairs,
// grid(3,768)) and KEEP r16's counter-verified wins:
//   - XOR slot-swizzle ybuf stride 72->64 (bank conflicts 2.95M -> 2.10M)
//   - biases folded into MFMA C-init (VALUBusy 68.4 -> 62.6 at const work)
//   - NEW: dxs[12] kept live from top; no x[jg] reload in shift phase.
// Next lever if this lands: register-resident activations (drop ybuf, MFMA
// B-frags in regs + cross-lane repack) to break the 12-wave latency wall.
//
// ws layout (float offsets):
#define WS_BJ    0         // Bj [768][64] f32
#define WS_BI    49152     // Bi [768][64] f32
#define WS_W0AT  98304     // W0a^T [64][4] f32
#define WS_BIAS  98560     // [224] f32: eb1@0, xb0@64, infb@128, 0, xb1@144, xb2@208, 0
#define WS_INFW  98784     // infw [64] f32
#define WS_WG    98848     // bf16 [224 rows][64]: W1^T@0, X0^T@64, infw@128, 0, X1^T@144, X2^T@208, 0
#define WS_PM    106016    // m_i partials [768][3][64] f32
#define WS_PS    253472    // shift partials [768][3][12] f32  (ends 281120)

typedef unsigned short ushort_t;
typedef __attribute__((ext_vector_type(8))) __bf16 bf16x8;
typedef __attribute__((ext_vector_type(4))) float f32x4;

__device__ __forceinline__ float silu_f(float v) {
    return v * __builtin_amdgcn_rcpf(1.0f + __expf(-v));
}
__device__ __forceinline__ float sigm_f(float v) {
    return __builtin_amdgcn_rcpf(1.0f + __expf(-v));
}

__device__ __forceinline__ ushort_t bf16r(float f) {
    unsigned u = __float_as_uint(f);
    u += 0x7FFFu + ((u >> 16) & 1u);
    return (ushort_t)(u >> 16);
}
__device__ __forceinline__ float bf2f(ushort_t s) { return __uint_as_float(((unsigned)s) << 16); }

__device__ __forceinline__ unsigned pk2(float a, float b) {
    __hip_bfloat162 t = __float22bfloat162_rn(make_float2(a, b));
    return *reinterpret_cast<unsigned*>(&t);
}

// swizzled element offset of the 8-ushort (16B) slot `slot` in row `row`
// of a [64][64] ushort tile. XOR by row&7 spreads the 8 slot-columns across
// banks for the strided (row-varying) access patterns.
__device__ __forceinline__ int ybo(int row, int slot) {
    return row * 64 + (((slot) ^ (row & 7)) << 3);
}
// f32 view of slot 0 of a row (16B = float4), same swizzle
__device__ __forceinline__ int yfo(int row) {
    return row * 32 + ((row & 7) << 2);
}

// ---------------- prep (256-thread blocks) ----------------
__global__ __launch_bounds__(256) void prep_kernel(
    const float* __restrict__ x, const float* __restrict__ h,
    const float* __restrict__ ew0, const float* __restrict__ eb0,
    const float* __restrict__ ew1, const float* __restrict__ eb1,
    const float* __restrict__ infw, const float* __restrict__ infb,
    const float* __restrict__ xw0, const float* __restrict__ xb0,
    const float* __restrict__ xw1, const float* __restrict__ xb1,
    const float* __restrict__ xw2, const float* __restrict__ xb2,
    float* __restrict__ ws)
{
    const int blk = blockIdx.x, tid = threadIdx.x;
    const int wv = tid >> 6, t = tid & 63;
    if (blk < 192) {
        __shared__ float hcs[4][80];
        const int m = blk * 4 + wv;
        hcs[wv][t] = h[m * 64 + t];
        if (t < 16) {
            int i2 = t >> 2, j2 = t & 3;
            float d0 = x[m*12 + j2*3 + 0] - x[m*12 + i2*3 + 0];
            float d1 = x[m*12 + j2*3 + 1] - x[m*12 + i2*3 + 1];
            float d2 = x[m*12 + j2*3 + 2] - x[m*12 + i2*3 + 2];
            hcs[wv][64 + t] = d0*d0 + d1*d1 + d2*d2;
        }
        float bj = 0.0f, bi = eb0[t];
        #pragma unroll 4
        for (int k = 0; k < 80; ++k) {
            float hv = hcs[wv][k];
            bj += hv * ew0[(4 + k) * 64 + t];
            bi += hv * ew0[(84 + k) * 64 + t];
        }
        ws[WS_BJ + m * 64 + t] = bj;
        ws[WS_BI + m * 64 + t] = bi;
    } else if (blk == 192) {
        if (wv == 0) {
            #pragma unroll
            for (int hh = 0; hh < 4; ++hh) ws[WS_W0AT + t * 4 + hh] = ew0[hh * 64 + t];
            ws[WS_INFW + t] = infw[t];
            #pragma unroll
            for (int u = 0; u < 4; ++u) {
                int idx = u * 64 + t;
                if (idx < 224) {
                    float v;
                    if (idx < 64)        v = eb1[idx];
                    else if (idx < 128)  v = xb0[idx - 64];
                    else if (idx == 128) v = infb[0];
                    else if (idx < 144)  v = 0.0f;
                    else if (idx < 208)  v = xb1[idx - 144];
                    else if (idx < 212)  v = xb2[idx - 208];
                    else                 v = 0.0f;
                    ws[WS_BIAS + idx] = v;
                }
            }
        }
    } else {
        ushort_t* wg = (ushort_t*)(ws + WS_WG);
        #pragma unroll 1
        for (int u = 0; u < 8; ++u) {
            int e = (blk - 193) * 2048 + tid * 8 + u;   // < 14336
            int r = e >> 6, k = e & 63;
            float v;
            if (r < 64)        v = ew1[k * 64 + r];
            else if (r < 128)  v = xw0[k * 64 + (r - 64)];
            else if (r == 128) v = infw[k];
            else if (r < 144)  v = 0.0f;
            else if (r < 208)  v = xw1[k * 64 + (r - 144)];
            else if (r < 212)  v = xw2[k * 4 + (r - 208)];
            else               v = 0.0f;
            wg[e] = bf16r(v);
        }
    }
}

// B-frags from per-wave swizzled LDS activations [p][k] (stride 64, xor slots)
__device__ __forceinline__ void load_bfrags(const ushort_t* yb, int ml, int q, bf16x8 B[4][2]) {
    #pragma unroll
    for (int pt = 0; pt < 4; ++pt)
        #pragma unroll
        for (int kt = 0; kt < 2; ++kt)
            B[pt][kt] = *(const bf16x8*)(yb + ybo(pt*16 + ml, kt*4 + q));
}

template<int NMT>
__device__ __forceinline__ void gemmG(const ushort_t* __restrict__ wg, int ml, int q,
                                      const bf16x8 B[4][2], f32x4* acc) {
    #pragma unroll
    for (int mt = 0; mt < NMT; ++mt) {
        #pragma unroll
        for (int kt = 0; kt < 2; ++kt) {
            bf16x8 af = *(const bf16x8*)(wg + (mt*16 + ml) * 64 + kt*32 + q*8);
            #pragma unroll
            for (int pt = 0; pt < 4; ++pt)
                acc[mt*4 + pt] = __builtin_amdgcn_mfma_f32_16x16x32_bf16(af, B[pt][kt], acc[mt*4 + pt], 0, 0, 0);
        }
    }
}

// bias already folded into acc init; just silu+pack+store (swizzled)
__device__ __forceinline__ void ep_silu2(ushort_t* yb, int ml, int q,
                                         const f32x4* acc, int coff) {
    #pragma unroll
    for (int mt = 0; mt < 2; ++mt) {
        #pragma unroll
        for (int pt = 0; pt < 4; ++pt) {
            f32x4 a = acc[mt*4 + pt];
            uint2 w = make_uint2(pk2(silu_f(a[0]), silu_f(a[1])),
                                 pk2(silu_f(a[2]), silu_f(a[3])));
            int row  = pt*16 + ml;
            int slot = (coff >> 3) + mt*2 + (q >> 1);
            *(uint2*)(yb + ybo(row, slot) + (q & 1) * 4) = w;
        }
    }
}

__device__ __forceinline__ void layer64(ushort_t* yb, const ushort_t* __restrict__ wg,
                                        const float* __restrict__ bias, int ml, int q) {
    bf16x8 B[4][2];
    load_bfrags(yb, ml, q, B);
    f32x4 acc[8];
    #pragma unroll
    for (int mt = 0; mt < 2; ++mt) {
        float4 bv = *(const float4*)(bias + mt*16 + q*4);
        #pragma unroll
        for (int pt = 0; pt < 4; ++pt) acc[mt*4 + pt] = f32x4{bv.x, bv.y, bv.z, bv.w};
    }
    gemmG<2>(wg, ml, q, B, acc);
    ep_silu2(yb, ml, q, acc, 0);
    #pragma unroll
    for (int mt = 0; mt < 2; ++mt) {
        float4 bv = *(const float4*)(bias + 32 + mt*16 + q*4);
        #pragma unroll
        for (int pt = 0; pt < 4; ++pt) acc[mt*4 + pt] = f32x4{bv.x, bv.y, bv.z, bv.w};
    }
    gemmG<2>(wg + 32*64, ml, q, B, acc);
    ep_silu2(yb, ml, q, acc, 32);
}

// ---------------- chunk kernel: block = (chunk it, row i), 256 pairs ----------------
__global__ __launch_bounds__(256, 2) void egcl_chunk(
    const float* __restrict__ x, float* __restrict__ ws)
{
    __shared__ __align__(16) ushort_t ybuf[4][4096];   // per-wave acts [64 p][64], 8 KB each
    __shared__ float sbuf[4][64];
    __shared__ float redm[4][64];
    __shared__ float reds[4][12];

    const int it = blockIdx.x, i = blockIdx.y, tid = threadIdx.x;
    const int wv = tid >> 6, lane = tid & 63;
    const int ml = lane & 15, q = lane >> 4;
    const int jg = it * 256 + wv * 64 + lane;

    const ushort_t* wg = (const ushort_t*)(ws + WS_WG);
    const float* bias  = ws + WS_BIAS;
    const float* infwf = ws + WS_INFW;
    ushort_t* yb = ybuf[wv];

    // xj - xi differences, kept live for the whole kernel (no reload in shift)
    float dxs[12];
    float sqn[4];
    {
        float xi[12];
        #pragma unroll
        for (int t = 0; t < 12; ++t) xi[t] = x[i * 12 + t];
        const float4* xp = (const float4*)(x + jg * 12);
        float4 a = xp[0], b = xp[1], c = xp[2];
        dxs[0]=a.x-xi[0]; dxs[1]=a.y-xi[1]; dxs[2]=a.z-xi[2];  dxs[3]=a.w-xi[3];
        dxs[4]=b.x-xi[4]; dxs[5]=b.y-xi[5]; dxs[6]=b.z-xi[6];  dxs[7]=b.w-xi[7];
        dxs[8]=c.x-xi[8]; dxs[9]=c.y-xi[9]; dxs[10]=c.z-xi[10];dxs[11]=c.w-xi[11];
        #pragma unroll
        for (int hh = 0; hh < 4; ++hh)
            sqn[hh] = dxs[hh*3+0]*dxs[hh*3+0] + dxs[hh*3+1]*dxs[hh*3+1]
                    + dxs[hh*3+2]*dxs[hh*3+2];
    }

    // ---- phi_e L0 (VALU, K=4 + Bi + Bj); write y0[p=lane][k] b128-packed ----
    {
        const float* Bi   = ws + WS_BI + i * 64;   // uniform -> s_load
        const float* w0at = ws + WS_W0AT;          // uniform -> s_load
        const float* Bj   = ws + WS_BJ + jg * 64;
        #pragma unroll
        for (int b = 0; b < 8; ++b) {
            float4 A = *(const float4*)(Bj + b*8);
            float4 Bv = *(const float4*)(Bj + b*8 + 4);
            float z[8] = {A.x, A.y, A.z, A.w, Bv.x, Bv.y, Bv.z, Bv.w};
            #pragma unroll
            for (int u = 0; u < 8; ++u) {
                int l = b*8 + u;
                float v = Bi[l] + z[u]
                        + sqn[0]*w0at[l*4+0] + sqn[1]*w0at[l*4+1]
                        + sqn[2]*w0at[l*4+2] + sqn[3]*w0at[l*4+3];
                z[u] = silu_f(v);
            }
            uint4 pkv = make_uint4(pk2(z[0],z[1]), pk2(z[2],z[3]),
                                   pk2(z[4],z[5]), pk2(z[6],z[7]));
            *(uint4*)(yb + ybo(lane, b)) = pkv;
        }
    }

    // ---- phi_e L1: m = silu(y0 @ W1 + b1) ----
    layer64(yb, wg + 0, bias + 0, ml, q);        // m -> yb

    // ---- phi_inf VALU row-dot: s_inf[p=lane] = infb + infw . m[lane][:] ----
    {
        float sv = bias[128];
        #pragma unroll
        for (int c = 0; c < 8; ++c) {
            int base = ybo(lane, c);
            uint2 w0 = *(const uint2*)(yb + base);
            uint2 w1 = *(const uint2*)(yb + base + 4);
            sv += __uint_as_float(w0.x << 16)          * infwf[c*8 + 0];
            sv += __uint_as_float(w0.x & 0xFFFF0000u)  * infwf[c*8 + 1];
            sv += __uint_as_float(w0.y << 16)          * infwf[c*8 + 2];
            sv += __uint_as_float(w0.y & 0xFFFF0000u)  * infwf[c*8 + 3];
            sv += __uint_as_float(w1.x << 16)          * infwf[c*8 + 4];
            sv += __uint_as_float(w1.x & 0xFFFF0000u)  * infwf[c*8 + 5];
            sv += __uint_as_float(w1.y << 16)          * infwf[c*8 + 6];
            sv += __uint_as_float(w1.y & 0xFFFF0000u)  * infwf[c*8 + 7];
        }
        sbuf[wv][lane] = (jg == i) ? 0.0f : sigm_f(sv);
    }

    // ---- m_i partial: lane=l sums e_p * m[p][l] (m still in yb) ----
    float macc = 0.0f;
    {
        const int g = lane >> 3, l7 = lane & 7;
        #pragma unroll 8
        for (int j2 = 0; j2 < 64; ++j2) {
            float ev = sbuf[wv][j2];
            macc += ev * bf2f(yb[j2*64 + (((g ^ (j2 & 7)) << 3) + l7)]);
        }
    }

    // ---- phi_x L0, L1 ----
    layer64(yb, wg + 64*64, bias + 64, ml, q);   // y1 -> yb
    layer64(yb, wg + 144*64, bias + 144, ml, q); // y2 -> yb

    // ---- phi_x L2 (64 -> 4); p overlaid into dead yb as f32 ----
    float* yf = (float*)yb;
    {
        bf16x8 B[4][2];
        load_bfrags(yb, ml, q, B);
        f32x4 acc2[4];
        float4 bx2 = *(const float4*)(bias + 208);
        #pragma unroll
        for (int t = 0; t < 4; ++t) acc2[t] = f32x4{bx2.x, bx2.y, bx2.z, bx2.w};
        gemmG<1>(wg + 208*64, ml, q, B, acc2);
        if (q == 0) {
            #pragma unroll
            for (int pt = 0; pt < 4; ++pt) {
                int row = pt*16 + ml;
                *(float4*)(yf + yfo(row)) =
                    make_float4(acc2[pt][0], acc2[pt][1], acc2[pt][2], acc2[pt][3]);
            }
        }
    }

    // ---- shift contributions (lane = p); butterfly -> reds ----
    {
        float4 pv = *(const float4*)(yf + yfo(lane));
        float pvh[4] = {pv.x, pv.y, pv.z, pv.w};
        float mask = (jg == i) ? 0.0f : 1.0f;
        float s12[12];
        #pragma unroll
        for (int hh = 0; hh < 4; ++hh) {
            float nsq = (sqn[hh] == 0.0f) ? 1.0f : sqn[hh];
            float inv = mask * pvh[hh] * __builtin_amdgcn_rcpf(sqrtf(nsq) + 1.0f);
            #pragma unroll
            for (int d = 0; d < 3; ++d)
                s12[hh*3 + d] = dxs[hh*3 + d] * inv;
        }
        #pragma unroll
        for (int t = 0; t < 12; ++t) {
            float v = s12[t];
            v += __shfl_xor(v, 1, 64);
            v += __shfl_xor(v, 2, 64);
            v += __shfl_xor(v, 4, 64);
            v += __shfl_xor(v, 8, 64);
            v += __shfl_xor(v, 16, 64);
            v += __shfl_xor(v, 32, 64);
            if (lane == 0) reds[wv][t] = v;
        }
    }

    redm[wv][lane] = macc;
    __syncthreads();

    if (wv == 0) {
        ws[WS_PM + (i*3 + it)*64 + lane] =
            redm[0][lane] + redm[1][lane] + redm[2][lane] + redm[3][lane];
        if (lane < 12)
            ws[WS_PS + (i*3 + it)*12 + lane] =
                reds[0][lane] + reds[1][lane] + reds[2][lane] + reds[3][lane];
    }
}

// ---------------- finish: sum partials + phi_h + x_new (4 nodes/block) ----------------
__global__ __launch_bounds__(256) void finish_kernel(
    const float* __restrict__ x, const float* __restrict__ h,
    const float* __restrict__ hw0, const float* __restrict__ hb0,
    const float* __restrict__ hw1, const float* __restrict__ hb1,
    const float* __restrict__ hw2, const float* __restrict__ hb2,
    const float* __restrict__ ws, float* __restrict__ out)
{
    __shared__ float inbuf[4][128];
    __shared__ float zbuf[4][64];
    const int tid = threadIdx.x;
    const int wv = tid >> 6, lane = tid & 63;
    const int i = blockIdx.x * 4 + wv;

    const float* pm = ws + WS_PM + i*3*64;
    float mi = (pm[lane] + pm[64 + lane] + pm[128 + lane]) * (1.0f / sqrtf(767.0f));
    inbuf[wv][lane] = mi;
    inbuf[wv][64 + lane] = h[i*64 + lane];

    if (lane < 12) {
        const float* ps = ws + WS_PS + i*3*12;
        float sh = ps[lane] + ps[12 + lane] + ps[24 + lane];
        out[i*12 + lane] = x[i*12 + lane] + sh * (1.0f / 767.0f);
    }

    // single wave per node: LDS ops in-order, no barrier needed
    float a = hb0[lane];
    #pragma unroll 8
    for (int k = 0; k < 128; ++k) a += inbuf[wv][k] * hw0[k*64 + lane];
    zbuf[wv][lane] = silu_f(a);

    a = hb1[lane];
    #pragma unroll 8
    for (int k = 0; k < 64; ++k) a += zbuf[wv][k] * hw1[k*64 + lane];
    zbuf[wv][lane] = silu_f(a);

    a = hb2[lane];
    #pragma unroll 8
    for (int k = 0; k < 64; ++k) a += zbuf[wv][k] * hw2[k*64 + lane];
    out[9216 + i*64 + lane] = h[i*64 + lane] + a;
}

extern "C" void kernel_launch(void* const* d_in, const int* in_sizes, int n_in,
                              void* d_out, int out_size, void* d_ws, size_t ws_size,
                              hipStream_t stream) {
    const float* x    = (const float*)d_in[0];
    const float* h    = (const float*)d_in[1];
    const float* ew0  = (const float*)d_in[2];
    const float* eb0  = (const float*)d_in[3];
    const float* ew1  = (const float*)d_in[4];
    const float* eb1  = (const float*)d_in[5];
    const float* infw = (const float*)d_in[6];
    const float* infb = (const float*)d_in[7];
    const float* xw0  = (const float*)d_in[8];
    const float* xb0  = (const float*)d_in[9];
    const float* xw1  = (const float*)d_in[10];
    const float* xb1  = (const float*)d_in[11];
    const float* xw2  = (const float*)d_in[12];
    const float* xb2  = (const float*)d_in[13];
    const float* hw0  = (const float*)d_in[14];
    const float* hb0  = (const float*)d_in[15];
    const float* hw1  = (const float*)d_in[16];
    const float* hb1  = (const float*)d_in[17];
    const float* hw2  = (const float*)d_in[18];
    const float* hb2  = (const float*)d_in[19];

    float* ws  = (float*)d_ws;
    float* out = (float*)d_out;

    prep_kernel<<<200, 256, 0, stream>>>(x, h, ew0, eb0, ew1, eb1, infw, infb,
                                         xw0, xb0, xw1, xb1, xw2, xb2, ws);
    egcl_chunk<<<dim3(3, 768), 256, 0, stream>>>(x, ws);
    finish_kernel<<<192, 256, 0, stream>>>(x, h, hw0, hb0, hw1, hb1, hw2, hb2, ws, out);
}

// Round 3
// 171.771 us; speedup vs baseline: 1.0111x; 1.0017x over previous
//
#include <hip/hip_runtime.h>
#include <hip/hip_bf16.h>
#include <math.h>

// N=768, H=4, D=3, HDIM=64, HID=64. e_in[i,j] = [sqn(4) | hc[j](80) | hc[i](80)]
// z0 = sqn@W0a + Bj[j] + Bi[i]  (Bi includes b0 and the hc[i] half).
// Round 18: r14 structure restored verbatim (stride-72 ybuf, immediate-offset
// LDS addressing, zero-init acc + bias-in-epilogue). r16/r17 showed the XOR
// swizzle is net-negative here: it trades (hidden) bank conflicts for computed
// LDS addresses on the MFMA dependency path — latency-bound kernel regressed
// 74.8 -> 94.5. Condemned; do not re-add. This round's minimal additions:
//   - phi_inf via MFMA (wg rows 128-143 were already infw zero-padded for
//     this): kills the serial 64-MAC row-dot; B-frags of m loaded ONCE and
//     reused for phi_x L0 (saves its 8 ds_read_b128 too).
//   - dxs[12] kept live from top (replaces xi liveness, same pressure);
//     no x[jg] reload in shift phase.
//
// ws layout (float offsets):
#define WS_BJ    0         // Bj [768][64] f32
#define WS_BI    49152     // Bi [768][64] f32
#define WS_W0AT  98304     // W0a^T [64][4] f32
#define WS_BIAS  98560     // [224] f32: eb1@0, xb0@64, infb@128, 0, xb1@144, xb2@208, 0
#define WS_INFW  98784     // infw [64] f32
#define WS_WG    98848     // bf16 [224 rows][64]: W1^T@0, X0^T@64, infw@128, 0, X1^T@144, X2^T@208, 0
#define WS_PM    106016    // m_i partials [768][3][64] f32
#define WS_PS    253472    // shift partials [768][3][12] f32  (ends 281120)

typedef unsigned short ushort_t;
typedef __attribute__((ext_vector_type(8))) __bf16 bf16x8;
typedef __attribute__((ext_vector_type(4))) float f32x4;

__device__ __forceinline__ float silu_f(float v) {
    return v * __builtin_amdgcn_rcpf(1.0f + __expf(-v));
}
__device__ __forceinline__ float sigm_f(float v) {
    return __builtin_amdgcn_rcpf(1.0f + __expf(-v));
}

__device__ __forceinline__ ushort_t bf16r(float f) {
    unsigned u = __float_as_uint(f);
    u += 0x7FFFu + ((u >> 16) & 1u);
    return (ushort_t)(u >> 16);
}
__device__ __forceinline__ float bf2f(ushort_t s) { return __uint_as_float(((unsigned)s) << 16); }

__device__ __forceinline__ unsigned pk2(float a, float b) {
    __hip_bfloat162 t = __float22bfloat162_rn(make_float2(a, b));
    return *reinterpret_cast<unsigned*>(&t);
}

// ---------------- prep (256-thread blocks) ----------------
__global__ __launch_bounds__(256) void prep_kernel(
    const float* __restrict__ x, const float* __restrict__ h,
    const float* __restrict__ ew0, const float* __restrict__ eb0,
    const float* __restrict__ ew1, const float* __restrict__ eb1,
    const float* __restrict__ infw, const float* __restrict__ infb,
    const float* __restrict__ xw0, const float* __restrict__ xb0,
    const float* __restrict__ xw1, const float* __restrict__ xb1,
    const float* __restrict__ xw2, const float* __restrict__ xb2,
    float* __restrict__ ws)
{
    const int blk = blockIdx.x, tid = threadIdx.x;
    const int wv = tid >> 6, t = tid & 63;
    if (blk < 192) {
        __shared__ float hcs[4][80];
        const int m = blk * 4 + wv;
        hcs[wv][t] = h[m * 64 + t];
        if (t < 16) {
            int i2 = t >> 2, j2 = t & 3;
            float d0 = x[m*12 + j2*3 + 0] - x[m*12 + i2*3 + 0];
            float d1 = x[m*12 + j2*3 + 1] - x[m*12 + i2*3 + 1];
            float d2 = x[m*12 + j2*3 + 2] - x[m*12 + i2*3 + 2];
            hcs[wv][64 + t] = d0*d0 + d1*d1 + d2*d2;
        }
        float bj = 0.0f, bi = eb0[t];
        #pragma unroll 4
        for (int k = 0; k < 80; ++k) {
            float hv = hcs[wv][k];
            bj += hv * ew0[(4 + k) * 64 + t];
            bi += hv * ew0[(84 + k) * 64 + t];
        }
        ws[WS_BJ + m * 64 + t] = bj;
        ws[WS_BI + m * 64 + t] = bi;
    } else if (blk == 192) {
        if (wv == 0) {
            #pragma unroll
            for (int hh = 0; hh < 4; ++hh) ws[WS_W0AT + t * 4 + hh] = ew0[hh * 64 + t];
            ws[WS_INFW + t] = infw[t];
            #pragma unroll
            for (int u = 0; u < 4; ++u) {
                int idx = u * 64 + t;
                if (idx < 224) {
                    float v;
                    if (idx < 64)        v = eb1[idx];
                    else if (idx < 128)  v = xb0[idx - 64];
                    else if (idx == 128) v = infb[0];
                    else if (idx < 144)  v = 0.0f;
                    else if (idx < 208)  v = xb1[idx - 144];
                    else if (idx < 212)  v = xb2[idx - 208];
                    else                 v = 0.0f;
                    ws[WS_BIAS + idx] = v;
                }
            }
        }
    } else {
        ushort_t* wg = (ushort_t*)(ws + WS_WG);
        #pragma unroll 1
        for (int u = 0; u < 8; ++u) {
            int e = (blk - 193) * 2048 + tid * 8 + u;   // < 14336
            int r = e >> 6, k = e & 63;
            float v;
            if (r < 64)        v = ew1[k * 64 + r];
            else if (r < 128)  v = xw0[k * 64 + (r - 64)];
            else if (r == 128) v = infw[k];
            else if (r < 144)  v = 0.0f;
            else if (r < 208)  v = xw1[k * 64 + (r - 144)];
            else if (r < 212)  v = xw2[k * 4 + (r - 208)];
            else               v = 0.0f;
            wg[e] = bf16r(v);
        }
    }
}

// B-frags from per-wave LDS activations [p][k], stride 72 (immediate offsets)
__device__ __forceinline__ void load_bfrags(const ushort_t* yb, int ml, int q, bf16x8 B[4][2]) {
    #pragma unroll
    for (int pt = 0; pt < 4; ++pt)
        #pragma unroll
        for (int kt = 0; kt < 2; ++kt)
            B[pt][kt] = *(const bf16x8*)(yb + (pt*16 + ml) * 72 + kt*32 + q*8);
}

template<int NMT>
__device__ __forceinline__ void gemmG(const ushort_t* __restrict__ wg, int ml, int q,
                                      const bf16x8 B[4][2], f32x4* acc) {
    #pragma unroll
    for (int mt = 0; mt < NMT; ++mt) {
        #pragma unroll
        for (int kt = 0; kt < 2; ++kt) {
            bf16x8 af = *(const bf16x8*)(wg + (mt*16 + ml) * 64 + kt*32 + q*8);
            #pragma unroll
            for (int pt = 0; pt < 4; ++pt)
                acc[mt*4 + pt] = __builtin_amdgcn_mfma_f32_16x16x32_bf16(af, B[pt][kt], acc[mt*4 + pt], 0, 0, 0);
        }
    }
}

__device__ __forceinline__ void ep_silu2(ushort_t* yb, int ml, int q,
                                         const f32x4* acc, const float* __restrict__ bias,
                                         int coff) {
    #pragma unroll
    for (int mt = 0; mt < 2; ++mt) {
        float4 bv = *(const float4*)(bias + coff + mt*16 + q*4);
        #pragma unroll
        for (int pt = 0; pt < 4; ++pt) {
            f32x4 a = acc[mt*4 + pt];
            uint2 w = make_uint2(pk2(silu_f(a[0] + bv.x), silu_f(a[1] + bv.y)),
                                 pk2(silu_f(a[2] + bv.z), silu_f(a[3] + bv.w)));
            *(uint2*)(yb + (pt*16 + ml) * 72 + coff + mt*16 + q*4) = w;
        }
    }
}

__device__ __forceinline__ void layer64(ushort_t* yb, const ushort_t* __restrict__ wg,
                                        const float* __restrict__ bias, int ml, int q) {
    bf16x8 B[4][2];
    load_bfrags(yb, ml, q, B);
    f32x4 acc[8];
    #pragma unroll
    for (int t = 0; t < 8; ++t) acc[t] = f32x4{0.f, 0.f, 0.f, 0.f};
    gemmG<2>(wg, ml, q, B, acc);
    ep_silu2(yb, ml, q, acc, bias, 0);
    #pragma unroll
    for (int t = 0; t < 8; ++t) acc[t] = f32x4{0.f, 0.f, 0.f, 0.f};
    gemmG<2>(wg + 32*64, ml, q, B, acc);
    ep_silu2(yb, ml, q, acc, bias, 32);
}

// ---------------- chunk kernel: block = (chunk it, row i), 256 pairs ----------------
__global__ __launch_bounds__(256, 2) void egcl_chunk(
    const float* __restrict__ x, float* __restrict__ ws)
{
    __shared__ ushort_t ybuf[4][4608];    // per-wave acts [64 p][72], 9 KB each
    __shared__ float sbuf[4][64];
    __shared__ float redm[4][64];
    __shared__ float reds[4][12];

    const int it = blockIdx.x, i = blockIdx.y, tid = threadIdx.x;
    const int wv = tid >> 6, lane = tid & 63;
    const int ml = lane & 15, q = lane >> 4;
    const int jg = it * 256 + wv * 64 + lane;

    const ushort_t* wg = (const ushort_t*)(ws + WS_WG);
    const float* bias  = ws + WS_BIAS;
    ushort_t* yb = ybuf[wv];

    // xj - xi differences, kept live for the whole kernel (no reload in shift)
    float dxs[12];
    float sqn[4];
    {
        float xi[12];
        #pragma unroll
        for (int t = 0; t < 12; ++t) xi[t] = x[i * 12 + t];
        const float4* xp = (const float4*)(x + jg * 12);
        float4 a = xp[0], b = xp[1], c = xp[2];
        dxs[0]=a.x-xi[0]; dxs[1]=a.y-xi[1]; dxs[2]=a.z-xi[2];  dxs[3]=a.w-xi[3];
        dxs[4]=b.x-xi[4]; dxs[5]=b.y-xi[5]; dxs[6]=b.z-xi[6];  dxs[7]=b.w-xi[7];
        dxs[8]=c.x-xi[8]; dxs[9]=c.y-xi[9]; dxs[10]=c.z-xi[10];dxs[11]=c.w-xi[11];
        #pragma unroll
        for (int hh = 0; hh < 4; ++hh)
            sqn[hh] = dxs[hh*3+0]*dxs[hh*3+0] + dxs[hh*3+1]*dxs[hh*3+1]
                    + dxs[hh*3+2]*dxs[hh*3+2];
    }

    // ---- phi_e L0 (VALU, K=4 + Bi + Bj); write y0[p=lane][k] b128-packed ----
    {
        const float* Bi   = ws + WS_BI + i * 64;   // uniform -> s_load
        const float* w0at = ws + WS_W0AT;          // uniform -> s_load
        const float* Bj   = ws + WS_BJ + jg * 64;
        #pragma unroll
        for (int b = 0; b < 8; ++b) {
            float4 A = *(const float4*)(Bj + b*8);
            float4 Bv = *(const float4*)(Bj + b*8 + 4);
            float z[8] = {A.x, A.y, A.z, A.w, Bv.x, Bv.y, Bv.z, Bv.w};
            #pragma unroll
            for (int u = 0; u < 8; ++u) {
                int l = b*8 + u;
                float v = Bi[l] + z[u]
                        + sqn[0]*w0at[l*4+0] + sqn[1]*w0at[l*4+1]
                        + sqn[2]*w0at[l*4+2] + sqn[3]*w0at[l*4+3];
                z[u] = silu_f(v);
            }
            uint4 pkv = make_uint4(pk2(z[0],z[1]), pk2(z[2],z[3]),
                                   pk2(z[4],z[5]), pk2(z[6],z[7]));
            *(uint4*)(yb + lane * 72 + b*8) = pkv;
        }
    }

    // ---- phi_e L1: m = silu(y0 @ W1 + b1) ----
    layer64(yb, wg + 0, bias + 0, ml, q);        // m -> yb

    // ---- B-frags of m, loaded ONCE; reused for phi_inf MFMA and phi_x L0 ----
    bf16x8 Bm[4][2];
    load_bfrags(yb, ml, q, Bm);

    // ---- phi_inf via MFMA: wg rows 128-143 = [infw; zeros]. Row 0 of C
    //      (lanes q==0, reg 0) holds infw . m[p][:] for p = pt*16 + ml. ----
    {
        f32x4 acc2[4];
        #pragma unroll
        for (int t = 0; t < 4; ++t) acc2[t] = f32x4{0.f, 0.f, 0.f, 0.f};
        gemmG<1>(wg + 128*64, ml, q, Bm, acc2);
        if (q == 0) {
            #pragma unroll
            for (int pt = 0; pt < 4; ++pt) {
                int p  = pt*16 + ml;
                int jj = it*256 + wv*64 + p;
                float sv = acc2[pt][0] + bias[128];   // + infb
                sbuf[wv][p] = (jj == i) ? 0.0f : sigm_f(sv);
            }
        }
    }

    // ---- m_i partial: lane=l sums e_p * m[p][l] (m still in yb) ----
    float macc = 0.0f;
    #pragma unroll 8
    for (int j2 = 0; j2 < 64; ++j2) {
        float ev = sbuf[wv][j2];
        macc += ev * bf2f(yb[j2 * 72 + lane]);
    }

    // ---- phi_x L0 (reuses Bm frags; no ds_read_b128 reload) ----
    {
        f32x4 acc[8];
        #pragma unroll
        for (int t = 0; t < 8; ++t) acc[t] = f32x4{0.f, 0.f, 0.f, 0.f};
        gemmG<2>(wg + 64*64, ml, q, Bm, acc);
        ep_silu2(yb, ml, q, acc, bias + 64, 0);
        #pragma unroll
        for (int t = 0; t < 8; ++t) acc[t] = f32x4{0.f, 0.f, 0.f, 0.f};
        gemmG<2>(wg + 64*64 + 32*64, ml, q, Bm, acc);
        ep_silu2(yb, ml, q, acc, bias + 64, 32);
    }

    // ---- phi_x L1 ----
    layer64(yb, wg + 144*64, bias + 144, ml, q); // y2 -> yb

    // ---- phi_x L2 (64 -> 4); p overlaid into dead yb as f32 ----
    float* yf = (float*)yb;
    {
        bf16x8 B[4][2];
        load_bfrags(yb, ml, q, B);
        f32x4 acc2[4];
        #pragma unroll
        for (int t = 0; t < 4; ++t) acc2[t] = f32x4{0.f, 0.f, 0.f, 0.f};
        gemmG<1>(wg + 208*64, ml, q, B, acc2);
        if (q == 0) {
            float4 bx2 = *(const float4*)(bias + 208);
            #pragma unroll
            for (int pt = 0; pt < 4; ++pt) {
                float4 pv = make_float4(acc2[pt][0] + bx2.x, acc2[pt][1] + bx2.y,
                                        acc2[pt][2] + bx2.z, acc2[pt][3] + bx2.w);
                *(float4*)(yf + (pt*16 + ml) * 4) = pv;
            }
        }
    }

    // ---- shift contributions (lane = p); butterfly -> reds ----
    {
        float4 pv = *(const float4*)(yf + lane * 4);
        float pvh[4] = {pv.x, pv.y, pv.z, pv.w};
        float mask = (jg == i) ? 0.0f : 1.0f;
        float s12[12];
        #pragma unroll
        for (int hh = 0; hh < 4; ++hh) {
            float nsq = (sqn[hh] == 0.0f) ? 1.0f : sqn[hh];
            float inv = mask * pvh[hh] * __builtin_amdgcn_rcpf(sqrtf(nsq) + 1.0f);
            #pragma unroll
            for (int d = 0; d < 3; ++d)
                s12[hh*3 + d] = dxs[hh*3 + d] * inv;
        }
        #pragma unroll
        for (int t = 0; t < 12; ++t) {
            float v = s12[t];
            v += __shfl_xor(v, 1, 64);
            v += __shfl_xor(v, 2, 64);
            v += __shfl_xor(v, 4, 64);
            v += __shfl_xor(v, 8, 64);
            v += __shfl_xor(v, 16, 64);
            v += __shfl_xor(v, 32, 64);
            if (lane == 0) reds[wv][t] = v;
        }
    }

    redm[wv][lane] = macc;
    __syncthreads();

    if (wv == 0) {
        ws[WS_PM + (i*3 + it)*64 + lane] =
            redm[0][lane] + redm[1][lane] + redm[2][lane] + redm[3][lane];
        if (lane < 12)
            ws[WS_PS + (i*3 + it)*12 + lane] =
                reds[0][lane] + reds[1][lane] + reds[2][lane] + reds[3][lane];
    }
}

// ---------------- finish: sum partials + phi_h + x_new (4 nodes/block) ----------------
__global__ __launch_bounds__(256) void finish_kernel(
    const float* __restrict__ x, const float* __restrict__ h,
    const float* __restrict__ hw0, const float* __restrict__ hb0,
    const float* __restrict__ hw1, const float* __restrict__ hb1,
    const float* __restrict__ hw2, const float* __restrict__ hb2,
    const float* __restrict__ ws, float* __restrict__ out)
{
    __shared__ float inbuf[4][128];
    __shared__ float zbuf[4][64];
    const int tid = threadIdx.x;
    const int wv = tid >> 6, lane = tid & 63;
    const int i = blockIdx.x * 4 + wv;

    const float* pm = ws + WS_PM + i*3*64;
    float mi = (pm[lane] + pm[64 + lane] + pm[128 + lane]) * (1.0f / sqrtf(767.0f));
    inbuf[wv][lane] = mi;
    inbuf[wv][64 + lane] = h[i*64 + lane];

    if (lane < 12) {
        const float* ps = ws + WS_PS + i*3*12;
        float sh = ps[lane] + ps[12 + lane] + ps[24 + lane];
        out[i*12 + lane] = x[i*12 + lane] + sh * (1.0f / 767.0f);
    }

    // single wave per node: LDS ops in-order, no barrier needed
    float a = hb0[lane];
    #pragma unroll 8
    for (int k = 0; k < 128; ++k) a += inbuf[wv][k] * hw0[k*64 + lane];
    zbuf[wv][lane] = silu_f(a);

    a = hb1[lane];
    #pragma unroll 8
    for (int k = 0; k < 64; ++k) a += zbuf[wv][k] * hw1[k*64 + lane];
    zbuf[wv][lane] = silu_f(a);

    a = hb2[lane];
    #pragma unroll 8
    for (int k = 0; k < 64; ++k) a += zbuf[wv][k] * hw2[k*64 + lane];
    out[9216 + i*64 + lane] = h[i*64 + lane] + a;
}

extern "C" void kernel_launch(void* const* d_in, const int* in_sizes, int n_in,
                              void* d_out, int out_size, void* d_ws, size_t ws_size,
                              hipStream_t stream) {
    const float* x    = (const float*)d_in[0];
    const float* h    = (const float*)d_in[1];
    const float* ew0  = (const float*)d_in[2];
    const float* eb0  = (const float*)d_in[3];
    const float* ew1  = (const float*)d_in[4];
    const float* eb1  = (const float*)d_in[5];
    const float* infw = (const float*)d_in[6];
    const float* infb = (const float*)d_in[7];
    const float* xw0  = (const float*)d_in[8];
    const float* xb0  = (const float*)d_in[9];
    const float* xw1  = (const float*)d_in[10];
    const float* xb1  = (const float*)d_in[11];
    const float* xw2  = (const float*)d_in[12];
    const float* xb2  = (const float*)d_in[13];
    const float* hw0  = (const float*)d_in[14];
    const float* hb0  = (const float*)d_in[15];
    const float* hw1  = (const float*)d_in[16];
    const float* hb1  = (const float*)d_in[17];
    const float* hw2  = (const float*)d_in[18];
    const float* hb2  = (const float*)d_in[19];

    float* ws  = (float*)d_ws;
    float* out = (float*)d_out;

    prep_kernel<<<200, 256, 0, stream>>>(x, h, ew0, eb0, ew1, eb1, infw, infb,
                                         xw0, xb0, xw1, xb1, xw2, xb2, ws);
    egcl_chunk<<<dim3(3, 768), 256, 0, stream>>>(x, ws);
    finish_kernel<<<192, 256, 0, stream>>>(x, h, hw0, hb0, hw1, hb1, hw2, hb2, ws, out);
}